// Round 10
// baseline (1203.457 us; speedup 1.0000x reference)
//
#include <hip/hip_runtime.h>
#include <math.h>

#define NN 40000
#define EE 640000
#define DD 128
#define EDD 16
#define LL 3
#define KPW 2      // dst nodes per task in edge_msg_kernel
#define NTASK (NN / KPW)
#define EMB 1280   // persistent blocks for edge_msg (≈5/CU at 32KB LDS)

__device__ __constant__ float kBnInv = 0.9999950000374997f; // 1/sqrt(1+1e-5)

typedef __bf16 bf16x8 __attribute__((ext_vector_type(8)));
typedef float  f32x16 __attribute__((ext_vector_type(16)));
typedef float  f32x4  __attribute__((ext_vector_type(4)));
typedef float  f32x2  __attribute__((ext_vector_type(2)));

// pack two floats to bf16 pair (RTNE) in one uint: lo16=a, hi16=b
__device__ __forceinline__ unsigned pack_bf2(float a, float b) {
    unsigned ua = __float_as_uint(a), ub = __float_as_uint(b);
    ua = (ua + 0x7fffu + ((ua >> 16) & 1u)) >> 16;
    ub = (ub + 0x7fffu + ((ub >> 16) & 1u)) & 0xffff0000u;
    return ua | ub;
}
__device__ __forceinline__ unsigned short bf16r(float x) {
    unsigned u = __float_as_uint(x);
    u = (u + 0x7fffu + ((u >> 16) & 1u)) >> 16;
    return (unsigned short)u;
}

// ---------------------------------------------------------------------------
// h = x @ node_W + node_b; emits h (fp32), hb (packed bf16), and the fused
// layer-0 attention partials pi/pj + z init (= (1+eps0)*h).
__global__ __launch_bounds__(256) void node_enc_kernel(
    const float* __restrict__ x, const float* __restrict__ W,
    const float* __restrict__ b,
    const float* __restrict__ aW, const float* __restrict__ eps_p,
    float* __restrict__ h, unsigned* __restrict__ hb,
    float* __restrict__ pi, float* __restrict__ pj, float* __restrict__ z)
{
    __shared__ float xs[32][DD];
    const int t = threadIdx.x;
    const long rowbase = (long)blockIdx.x * 32;

    const float4* x4 = (const float4*)(x + rowbase * DD);
    float4* xs4 = (float4*)&xs[0][0];
#pragma unroll
    for (int i = 0; i < 4; i++) xs4[t + i * 256] = x4[t + i * 256];
    __syncthreads();

    const int c  = (t & 31) * 4;
    const int r0 = (t >> 5) * 4;

    float acc[4][4] = {};
    for (int k4 = 0; k4 < DD; k4 += 4) {
        float4 xr[4];
#pragma unroll
        for (int i = 0; i < 4; i++) xr[i] = *(const float4*)&xs[r0 + i][k4];
#pragma unroll
        for (int kk = 0; kk < 4; kk++) {
            const float4 w = *(const float4*)(W + (k4 + kk) * DD + c);
#pragma unroll
            for (int i = 0; i < 4; i++) {
                const float xv = ((const float*)&xr[i])[kk];
                acc[i][0] = fmaf(xv, w.x, acc[i][0]);
                acc[i][1] = fmaf(xv, w.y, acc[i][1]);
                acc[i][2] = fmaf(xv, w.z, acc[i][2]);
                acc[i][3] = fmaf(xv, w.w, acc[i][3]);
            }
        }
    }
    const float4 bv  = *(const float4*)(b + c);
    const float4 awi = *(const float4*)(aW + c);
    const float4 awj = *(const float4*)(aW + DD + c);
    const float ep = 1.0f + eps_p[0];

    float pa[4], pb[4];
#pragma unroll
    for (int i = 0; i < 4; i++) {
        const long row = rowbase + r0 + i;
        float4 ov = { acc[i][0] + bv.x, acc[i][1] + bv.y,
                      acc[i][2] + bv.z, acc[i][3] + bv.w };
        *(float4*)(h + row * DD + c) = ov;
        uint2 pv = { pack_bf2(ov.x, ov.y), pack_bf2(ov.z, ov.w) };
        *(uint2*)(hb + row * 64 + (c >> 1)) = pv;
        float4 zv = { ep * ov.x, ep * ov.y, ep * ov.z, ep * ov.w };
        *(float4*)(z + row * DD + c) = zv;
        pa[i] = ov.x * awi.x + ov.y * awi.y + ov.z * awi.z + ov.w * awi.w;
        pb[i] = ov.x * awj.x + ov.y * awj.y + ov.z * awj.z + ov.w * awj.w;
    }
#pragma unroll
    for (int off = 1; off < 32; off <<= 1) {
#pragma unroll
        for (int i = 0; i < 4; i++) {
            pa[i] += __shfl_xor(pa[i], off, 64);
            pb[i] += __shfl_xor(pb[i], off, 64);
        }
    }
    if ((t & 31) == 0) {
#pragma unroll
        for (int i = 0; i < 4; i++) {
            pi[rowbase + r0 + i] = pa[i];
            pj[rowbase + r0 + i] = pb[i];
        }
    }
}

// ---------------------------------------------------------------------------
// weight transpose + bf16 cast (W1, W2, and edge_W -> col-major bf16)
__global__ __launch_bounds__(256) void wcast_kernel(
    const float* __restrict__ W1, const float* __restrict__ W2,
    const float* __restrict__ eW,
    unsigned short* __restrict__ w1t, unsigned short* __restrict__ w2t,
    unsigned short* __restrict__ ewt)
{
    const int idx = blockIdx.x * 256 + threadIdx.x;   // grid covers LL*32768
    const int l = idx >> 15, r = idx & 32767;
    {   const int n = r >> 7, k = r & 127;
        w1t[idx] = bf16r(W1[(l << 15) + (k << 8) + n]);
    }
    {   const int n = r >> 8, k = r & 255;
        w2t[idx] = bf16r(W2[(l << 15) + (k << 7) + n]);
    }
    if (idx < LL * 2048) {                            // ewt[l][n][k], n<128,k<16
        const int le = idx >> 11, re = idx & 2047;
        const int n = re >> 4, k = re & 15;
        ewt[idx] = bf16r(eW[(le << 11) + (k << 7) + n]);
    }
}

// ---------------------------------------------------------------------------
// CSR build
__global__ __launch_bounds__(256) void hist_kernel(
    const int* __restrict__ edge_index, int* __restrict__ counts)
{
    const int i = blockIdx.x * 256 + threadIdx.x;
    atomicAdd(&counts[edge_index[EE + i]], 1);
}

__global__ __launch_bounds__(256) void scan1_kernel(
    const int* __restrict__ counts, int* __restrict__ scanned,
    int* __restrict__ partials)
{
    __shared__ int sdata[256];
    const int t = threadIdx.x;
    const int base = blockIdx.x * 1024 + t * 4;
    int v[4]; int sum = 0;
#pragma unroll
    for (int i = 0; i < 4; i++) {
        const int idx = base + i;
        v[i] = (idx < NN) ? counts[idx] : 0;
        sum += v[i];
    }
    sdata[t] = sum;
    __syncthreads();
    for (int off = 1; off < 256; off <<= 1) {
        int x = (t >= off) ? sdata[t - off] : 0;
        __syncthreads();
        sdata[t] += x;
        __syncthreads();
    }
    int run = sdata[t] - sum;
#pragma unroll
    for (int i = 0; i < 4; i++) {
        const int idx = base + i;
        if (idx < NN) scanned[idx] = run;
        run += v[i];
    }
    if (t == 255) partials[blockIdx.x] = sdata[255];
}

__global__ void scan2_kernel(int* __restrict__ partials)
{
    if (threadIdx.x == 0) {
        int run = 0;
        for (int i = 0; i < 40; i++) { int v = partials[i]; partials[i] = run; run += v; }
    }
}

__global__ __launch_bounds__(256) void scan3_kernel(
    const int* __restrict__ scanned, const int* __restrict__ partials,
    int* __restrict__ offsets, int* __restrict__ cursor)
{
    const int idx = blockIdx.x * 256 + threadIdx.x;
    if (idx < NN) {
        const int off = scanned[idx] + partials[idx >> 10];
        offsets[idx] = off;
        cursor[idx]  = off;
    }
}

// scatter: pre-scaled src/dst streams + bf16-packed edge_attr at CSR position
__global__ __launch_bounds__(256) void scatter_kernel(
    const int* __restrict__ edge_index, const float* __restrict__ edge_attr,
    int* __restrict__ cursor,
    int* __restrict__ srcs_p, int* __restrict__ dstd_p,
    unsigned* __restrict__ ea_b)
{
    const int i = blockIdx.x * 256 + threadIdx.x;
    const int src = edge_index[i];
    const int dst = edge_index[EE + i];
    const int pos = atomicAdd(&cursor[dst], 1);
    srcs_p[pos] = src << 6;
    dstd_p[pos] = dst << 7;

    const float4* sp = (const float4*)(edge_attr + (long)i * EDD);
    const float4 s0 = sp[0], s1 = sp[1], s2 = sp[2], s3 = sp[3];
    uint4 o0 = { pack_bf2(s0.x, s0.y), pack_bf2(s0.z, s0.w),
                 pack_bf2(s1.x, s1.y), pack_bf2(s1.z, s1.w) };
    uint4 o1 = { pack_bf2(s2.x, s2.y), pack_bf2(s2.z, s2.w),
                 pack_bf2(s3.x, s3.y), pack_bf2(s3.z, s3.w) };
    *(uint4*)(ea_b + (long)pos * 8)     = o0;
    *(uint4*)(ea_b + (long)pos * 8 + 4) = o1;
}

// ---------------------------------------------------------------------------
// Edge aggregation v9 = v7 (best measured: 68.5us) + persistent-wave WORK
// QUEUE: 1280 blocks of persistent waves pull node-pair tasks (20000) from a
// global atomic counter -> no block-tail decay (v7 time-avg occupancy 31% vs
// 62.5% cap was the remaining anomaly). Everything inside the task loop is
// byte-identical to v7; bfr/ebv are task-invariant and hoisted.
__global__ __launch_bounds__(256, 2) void edge_msg_kernel(
    const unsigned* __restrict__ hb, const unsigned* __restrict__ ea_b,
    const float* __restrict__ pi, const float* __restrict__ pj,
    const int* __restrict__ srcs_p, const int* __restrict__ dstd_p,
    const int* __restrict__ offsets, const float* __restrict__ ab_p,
    const unsigned short* __restrict__ eWt, const float* __restrict__ eb,
    float* __restrict__ z, int* __restrict__ wq)
{
    __shared__ __align__(16) unsigned short et[4][32 * DD];   // 8 KB per wave

    const int t = threadIdx.x;
    const int wid = t >> 6, lane = t & 63;

    const int l31 = lane & 31, half = lane >> 5;
    bf16x8 bfr[4];
#pragma unroll
    for (int nt = 0; nt < 4; nt++)
        bfr[nt] = *(const bf16x8*)(eWt + (nt * 32 + l31) * 16 + half * 8);
    float ebv[4];
#pragma unroll
    for (int nt = 0; nt < 4; nt++) ebv[nt] = eb[nt * 32 + l31];
    const float ab0 = ab_p[0];
    const int rb = 4 * half;                 // MFMA C row base (32x32 layout)
    unsigned short* etw = et[wid];
    const int c0 = lane * 2;
    const f32x2 zero2 = { 0.0f, 0.0f };
    const f32x16 vz16 = {0.0f,0.0f,0.0f,0.0f, 0.0f,0.0f,0.0f,0.0f,
                         0.0f,0.0f,0.0f,0.0f, 0.0f,0.0f,0.0f,0.0f};

    // ---- persistent task loop ----
    int task;
    if (lane == 0) task = atomicAdd(wq, 1);
    task = __shfl(task, 0, 64);

    while (task < NTASK) {
        const int n0 = task * KPW;
        const int ebeg = offsets[n0];
        const int eend = (n0 + KPW < NN) ? offsets[n0 + KPW] : EE;

        f32x2 acc = zero2;
        int cur = -1;                        // current dst (as dst*128), uniform

        for (int e = ebeg; e < eend; e += 32) {
            const int rem = eend - e;
            const int nv = rem < 32 ? rem : 32;

            // ---- meta for 32 edges on lanes (duplicated across halves) ----
            const int ce = min(e + l31, EE - 1);
            const int ss = srcs_p[ce];       // src*64
            const int dd = dstd_p[ce];       // dst*128
            const float s  = pi[dd >> 7] + pj[ss >> 6] + ab0;
            const float av = 1.0f / (1.0f + expf(-s));
            const unsigned avu = __float_as_uint(av);

            // helper: consume one edge (index j in tile, gathered word uj).
            // j is a compile-time constant at every call site -> v_readlane.
            auto consume = [&](int j, unsigned uj) {
                const int ddj = __builtin_amdgcn_readlane(dd, j);
                if (ddj != cur) {            // wave-uniform (scalar compare)
                    if (cur >= 0) {
                        float2 zv = *(const float2*)(z + cur + c0);
                        zv.x += acc[0]; zv.y += acc[1];
                        *(float2*)(z + cur + c0) = zv;
                    }
                    acc = zero2; cur = ddj;
                }
                const float aj = __uint_as_float(__builtin_amdgcn_readlane(avu, j));
                const unsigned el = (unsigned)etw[j * DD + c0];
                const unsigned eh = (unsigned)etw[j * DD + c0 + 1];
                const f32x2 ev = { __uint_as_float(el << 16),
                                   __uint_as_float(eh << 16) };
                const f32x2 xj = { __uint_as_float(uj << 16),
                                   __uint_as_float(uj & 0xffff0000u) };
                const f32x2 avv = { aj, aj };
                f32x2 m = __builtin_elementwise_fma(xj, avv, ev);
                m = __builtin_elementwise_max(m, zero2);
                acc += m;
            };

            // ---- gather half 0 early; drains under the MFMA phase ----
            unsigned u0[16];
#pragma unroll
            for (int j = 0; j < 16; j++)
                if (j < nv) u0[j] = hb[__shfl(ss, j, 64) + lane];

            // ---- e = ea @ eW + eb on matrix pipe -> wave-private bf16 LDS ----
            const bf16x8 afr = *(const bf16x8*)(ea_b + (long)ce * 8 + half * 4);
#pragma unroll
            for (int p = 0; p < 2; p++) {
                f32x16 a0 = vz16, a1 = vz16;
                a0 = __builtin_amdgcn_mfma_f32_32x32x16_bf16(afr, bfr[2 * p],     a0, 0, 0, 0);
                a1 = __builtin_amdgcn_mfma_f32_32x32x16_bf16(afr, bfr[2 * p + 1], a1, 0, 0, 0);
#pragma unroll
                for (int r = 0; r < 16; r++) {
                    const int row = rb + (r & 3) + 8 * (r >> 2);
                    etw[row * DD + (2 * p)     * 32 + l31] = bf16r(a0[r] + ebv[2 * p]);
                    etw[row * DD + (2 * p + 1) * 32 + l31] = bf16r(a1[r] + ebv[2 * p + 1]);
                }
            }
            asm volatile("" ::: "memory");   // phase fence: stores before loads

            // ---- gather half 1; drains under consume of half 0 ----
            unsigned u1[16];
#pragma unroll
            for (int j = 0; j < 16; j++)
                if (16 + j < nv) u1[j] = hb[__shfl(ss, 16 + j, 64) + lane];

            // ---- consume half 0, then half 1 ----
#pragma unroll
            for (int j = 0; j < 16; j++) {
                if (j >= nv) break;          // wave-uniform
                consume(j, u0[j]);
            }
#pragma unroll
            for (int j = 0; j < 16; j++) {
                if (16 + j >= nv) break;     // wave-uniform
                consume(16 + j, u1[j]);
            }
            asm volatile("" ::: "memory");   // phase fence: loads before next stores
        }
        if (cur >= 0) {
            float2 zv = *(const float2*)(z + cur + c0);
            zv.x += acc[0]; zv.y += acc[1];
            *(float2*)(z + cur + c0) = zv;
        }

        if (lane == 0) task = atomicAdd(wq, 1);
        task = __shfl(task, 0, 64);
    }
}

// ---------------------------------------------------------------------------
// Fused GIN MLP via bf16 MFMA, N-SPLIT: each wave owns 4 col-tiles (phase 1)
// / 2 col-tiles (phase 2) for ALL 64 rows -> no cross-wave weight redundancy.
// Epilogue 2 also produces next-layer pi/pj (LDS-reduced) and z init.
__global__ __launch_bounds__(256) void mlp_mfma_kernel(
    const float* __restrict__ zin,
    const unsigned short* __restrict__ w1t, const unsigned short* __restrict__ w2t,
    const float* __restrict__ b1, const float* __restrict__ g1, const float* __restrict__ bb1,
    const float* __restrict__ b2, const float* __restrict__ g2, const float* __restrict__ bb2,
    const float* __restrict__ aWn, const float* __restrict__ epsn_p,
    float* __restrict__ out, unsigned* __restrict__ hb,
    float* __restrict__ pi, float* __restrict__ pj, float* __restrict__ z,
    const int do_relu)
{
    __shared__ __align__(16) unsigned short zsb[64][136];   // 128 + 8 pad
    __shared__ __align__(16) unsigned short usb[64][264];   // 256 + 8 pad
    __shared__ float sh_pi[64], sh_pj[64];
    const int t = threadIdx.x;
    const int wid = t >> 6, lane = t & 63;
    const long rowbase = (long)blockIdx.x * 64;

    if (t < 64) { sh_pi[t] = 0.0f; sh_pj[t] = 0.0f; }

    // stage z (fp32) -> zsb (bf16)
    {
        const float4* z4 = (const float4*)(zin + rowbase * DD);
#pragma unroll
        for (int i = 0; i < 8; i++) {
            const int idx = t + i * 256;          // 2048 float4 = 64x128
            const float4 v = z4[idx];
            const int row = idx >> 5;
            const int c4  = (idx & 31) * 4;
            uint2 pv = { pack_bf2(v.x, v.y), pack_bf2(v.z, v.w) };
            *(uint2*)&zsb[row][c4] = pv;
        }
    }
    __syncthreads();

    const int mrow  = lane & 15;
    const int quad  = lane >> 4;
    const f32x4 vzero = {0.0f, 0.0f, 0.0f, 0.0f};

    // ---- phase 1: wave owns nt = wid*4 .. wid*4+3 (cols) for all 64 rows ----
    {
        const int nt0 = wid * 4;
        bf16x8 bf[4][4];                      // [j][ks]
#pragma unroll
        for (int j = 0; j < 4; j++) {
            const unsigned short* wp = w1t + ((nt0 + j) * 16 + mrow) * 128 + quad * 8;
#pragma unroll
            for (int ks = 0; ks < 4; ks++)
                bf[j][ks] = *(const bf16x8*)(wp + ks * 32);
        }
        float gg[4], bi[4], bt[4];
#pragma unroll
        for (int j = 0; j < 4; j++) {
            const int c = (nt0 + j) * 16 + mrow;
            gg[j] = g1[c]; bi[j] = b1[c]; bt[j] = bb1[c];
        }
#pragma unroll
        for (int rt = 0; rt < 4; rt++) {
            bf16x8 af[4];
#pragma unroll
            for (int ks = 0; ks < 4; ks++)
                af[ks] = *(const bf16x8*)&zsb[rt * 16 + mrow][ks * 32 + quad * 8];
            f32x4 acc[4];
#pragma unroll
            for (int j = 0; j < 4; j++) acc[j] = vzero;
#pragma unroll
            for (int j = 0; j < 4; j++)
#pragma unroll
                for (int ks = 0; ks < 4; ks++)
                    acc[j] = __builtin_amdgcn_mfma_f32_16x16x32_bf16(af[ks], bf[j][ks], acc[j], 0, 0, 0);
            // epilogue 1 for this row tile
#pragma unroll
            for (int j = 0; j < 4; j++) {
                const int c = (nt0 + j) * 16 + mrow;
#pragma unroll
                for (int r = 0; r < 4; r++) {
                    const int row = rt * 16 + quad * 4 + r;
                    const float u = fmaxf(fmaf(gg[j] * (acc[j][r] + bi[j]), kBnInv, bt[j]), 0.0f);
                    const float up = __shfl_xor(u, 1, 64);
                    if ((mrow & 1) == 0)
                        *(unsigned*)&usb[row][c] = pack_bf2(u, up);
                }
            }
        }
    }
    __syncthreads();

    // ---- phase 2: wave owns nt = wid*2, wid*2+1 for all 64 rows ----
    {
        const int nt0 = wid * 2;
        bf16x8 bf[2][8];
#pragma unroll
        for (int j = 0; j < 2; j++) {
            const unsigned short* wp = w2t + ((nt0 + j) * 16 + mrow) * 256 + quad * 8;
#pragma unroll
            for (int ks = 0; ks < 8; ks++)
                bf[j][ks] = *(const bf16x8*)(wp + ks * 32);
        }
        float gg[2], bi[2], bt[2], awi[2], awj[2];
#pragma unroll
        for (int j = 0; j < 2; j++) {
            const int c = (nt0 + j) * 16 + mrow;
            gg[j] = g2[c]; bi[j] = b2[c]; bt[j] = bb2[c];
            awi[j] = aWn[c]; awj[j] = aWn[DD + c];
        }
        const float epn = do_relu ? (1.0f + epsn_p[0]) : 0.0f;

#pragma unroll
        for (int rt = 0; rt < 4; rt++) {
            bf16x8 af[8];
#pragma unroll
            for (int ks = 0; ks < 8; ks++)
                af[ks] = *(const bf16x8*)&usb[rt * 16 + mrow][ks * 32 + quad * 8];
            f32x4 acc[2];
            acc[0] = vzero; acc[1] = vzero;
#pragma unroll
            for (int j = 0; j < 2; j++)
#pragma unroll
                for (int ks = 0; ks < 8; ks++)
                    acc[j] = __builtin_amdgcn_mfma_f32_16x16x32_bf16(af[ks], bf[j][ks], acc[j], 0, 0, 0);

            float si[4] = {0, 0, 0, 0}, sj[4] = {0, 0, 0, 0};
#pragma unroll
            for (int j = 0; j < 2; j++) {
                const int c = (nt0 + j) * 16 + mrow;
#pragma unroll
                for (int r = 0; r < 4; r++) {
                    const long row = rowbase + rt * 16 + quad * 4 + r;
                    float v = fmaf(gg[j] * (acc[j][r] + bi[j]), kBnInv, bt[j]);
                    if (do_relu) {
                        v = fmaxf(v, 0.0f);
                        z[row * DD + c] = epn * v;
                        si[r] = fmaf(v, awi[j], si[r]);
                        sj[r] = fmaf(v, awj[j], sj[r]);
                    }
                    out[row * DD + c] = v;
                    const float vp = __shfl_xor(v, 1, 64);
                    if ((mrow & 1) == 0)
                        hb[row * 64 + (c >> 1)] = pack_bf2(v, vp);
                }
            }
            if (do_relu) {
#pragma unroll
                for (int off = 1; off < 16; off <<= 1) {
#pragma unroll
                    for (int r = 0; r < 4; r++) {
                        si[r] += __shfl_xor(si[r], off, 64);
                        sj[r] += __shfl_xor(sj[r], off, 64);
                    }
                }
                if (mrow == 0) {
#pragma unroll
                    for (int r = 0; r < 4; r++) {
                        atomicAdd(&sh_pi[rt * 16 + quad * 4 + r], si[r]);
                        atomicAdd(&sh_pj[rt * 16 + quad * 4 + r], sj[r]);
                    }
                }
            }
        }
    }
    if (do_relu) {
        __syncthreads();
        if (t < 64) {
            pi[rowbase + t] = sh_pi[t];
            pj[rowbase + t] = sh_pj[t];
        }
    }
}

// ---------------------------------------------------------------------------
extern "C" void kernel_launch(void* const* d_in, const int* in_sizes, int n_in,
                              void* d_out, int out_size, void* d_ws, size_t ws_size,
                              hipStream_t stream)
{
    const float* x         = (const float*)d_in[0];
    const float* edge_attr = (const float*)d_in[1];
    const float* node_W    = (const float*)d_in[2];
    const float* node_b    = (const float*)d_in[3];
    const float* edge_W    = (const float*)d_in[4];
    const float* edge_b    = (const float*)d_in[5];
    const float* attn_W    = (const float*)d_in[6];
    const float* attn_b    = (const float*)d_in[7];
    const float* eps       = (const float*)d_in[8];
    const float* W1        = (const float*)d_in[9];
    const float* b1        = (const float*)d_in[10];
    const float* bn1_g     = (const float*)d_in[11];
    const float* bn1_b     = (const float*)d_in[12];
    const float* W2        = (const float*)d_in[13];
    const float* b2        = (const float*)d_in[14];
    const float* bn_g      = (const float*)d_in[15];
    const float* bn_b      = (const float*)d_in[16];
    const int*   edge_index= (const int*)d_in[17];

    float* h    = (float*)d_ws;                          // [N*D]
    float* z    = h + (size_t)NN * DD;                   // [N*D]
    float* pi   = z + (size_t)NN * DD;                   // [N]
    float* pj   = pi + NN;                               // [N]
    unsigned* ea_b = (unsigned*)(pj + NN);               // [E*8] packed bf16
    unsigned* hbuf = ea_b + (size_t)EE * 8;              // [N*64]
    unsigned short* w1t = (unsigned short*)(hbuf + (size_t)NN * 64); // [L*32768]
    unsigned short* w2t = w1t + (size_t)LL * 32768;                  // [L*32768]
    unsigned short* ewt = w2t + (size_t)LL * 32768;      // [L*2048] eW col-major bf16
    int* counts  = (int*)(ewt + (size_t)LL * 2048);      // [N]
    int* offsets = counts + NN;                          // [N]
    int* cursor  = offsets + NN;                         // [N]
    int* scanned = cursor + NN;                          // [40960]
    int* partials= scanned + 40960;                      // [64]
    int* wq      = partials + 64;                        // [LL] work-queue heads
    int* srcs_p  = wq + 64;                              // [E] (src*64)
    int* dstd_p  = srcs_p + EE;                          // [E] (dst*128)
    float* out = (float*)d_out;

    node_enc_kernel<<<NN / 32, 256, 0, stream>>>(
        x, node_W, node_b, attn_W, eps, h, hbuf, pi, pj, z);
    wcast_kernel<<<LL * 128, 256, 0, stream>>>(W1, W2, edge_W, w1t, w2t, ewt);

    hipMemsetAsync(counts, 0, NN * sizeof(int), stream);
    hipMemsetAsync(wq, 0, LL * sizeof(int), stream);
    hist_kernel<<<EE / 256, 256, 0, stream>>>(edge_index, counts);
    scan1_kernel<<<40, 256, 0, stream>>>(counts, scanned, partials);
    scan2_kernel<<<1, 64, 0, stream>>>(partials);
    scan3_kernel<<<(NN + 255) / 256, 256, 0, stream>>>(scanned, partials, offsets, cursor);
    scatter_kernel<<<EE / 256, 256, 0, stream>>>(
        edge_index, edge_attr, cursor, srcs_p, dstd_p, ea_b);

    for (int l = 0; l < LL; l++) {
        const int ln = (l + 1 < LL) ? (l + 1) : l;   // next-layer attn/eps (dummy at last)
        edge_msg_kernel<<<EMB, 256, 0, stream>>>(
            hbuf, ea_b, pi, pj, srcs_p, dstd_p, offsets, attn_b + l,
            ewt + (size_t)l * 2048, edge_b + (size_t)l * DD, z, wq + l);
        mlp_mfma_kernel<<<NN / 64, 256, 0, stream>>>(
            z,
            w1t + (size_t)l * 32768, w2t + (size_t)l * 32768,
            b1 + (size_t)l * 2 * DD, bn1_g + (size_t)l * 2 * DD, bn1_b + (size_t)l * 2 * DD,
            b2 + (size_t)l * DD, bn_g + (size_t)l * DD, bn_b + (size_t)l * DD,
            attn_W + (size_t)ln * 2 * DD, eps + ln,
            (l == LL - 1) ? out : h, hbuf, pi, pj, z, (l < LL - 1) ? 1 : 0);
    }
}

// Round 11
// 501.075 us; speedup vs baseline: 2.4018x; 2.4018x over previous
//
#include <hip/hip_runtime.h>
#include <math.h>

#define NN 40000
#define EE 640000
#define DD 128
#define EDD 16
#define LL 3
#define KPW 2    // dst nodes owned per wave in edge_msg_kernel

__device__ __constant__ float kBnInv = 0.9999950000374997f; // 1/sqrt(1+1e-5)

typedef __bf16 bf16x8 __attribute__((ext_vector_type(8)));
typedef float  f32x16 __attribute__((ext_vector_type(16)));
typedef float  f32x4  __attribute__((ext_vector_type(4)));
typedef float  f32x2  __attribute__((ext_vector_type(2)));

// pack two floats to bf16 pair (RTNE) in one uint: lo16=a, hi16=b
__device__ __forceinline__ unsigned pack_bf2(float a, float b) {
    unsigned ua = __float_as_uint(a), ub = __float_as_uint(b);
    ua = (ua + 0x7fffu + ((ua >> 16) & 1u)) >> 16;
    ub = (ub + 0x7fffu + ((ub >> 16) & 1u)) & 0xffff0000u;
    return ua | ub;
}
__device__ __forceinline__ unsigned short bf16r(float x) {
    unsigned u = __float_as_uint(x);
    u = (u + 0x7fffu + ((u >> 16) & 1u)) >> 16;
    return (unsigned short)u;
}

// ---------------------------------------------------------------------------
// h = x @ node_W + node_b; emits hb (packed bf16), layer-0 attention partials
// pi/pj, and bf16-packed z init (= (1+eps0)*h). The fp32 h buffer was dead
// (nothing reads it) -> dropped (-20.5MB writes); z is bf16-packed (-10.5MB).
__global__ __launch_bounds__(256) void node_enc_kernel(
    const float* __restrict__ x, const float* __restrict__ W,
    const float* __restrict__ b,
    const float* __restrict__ aW, const float* __restrict__ eps_p,
    unsigned* __restrict__ hb,
    float* __restrict__ pi, float* __restrict__ pj, unsigned* __restrict__ zb)
{
    __shared__ float xs[32][DD];
    const int t = threadIdx.x;
    const long rowbase = (long)blockIdx.x * 32;

    const float4* x4 = (const float4*)(x + rowbase * DD);
    float4* xs4 = (float4*)&xs[0][0];
#pragma unroll
    for (int i = 0; i < 4; i++) xs4[t + i * 256] = x4[t + i * 256];
    __syncthreads();

    const int c  = (t & 31) * 4;
    const int r0 = (t >> 5) * 4;

    float acc[4][4] = {};
    for (int k4 = 0; k4 < DD; k4 += 4) {
        float4 xr[4];
#pragma unroll
        for (int i = 0; i < 4; i++) xr[i] = *(const float4*)&xs[r0 + i][k4];
#pragma unroll
        for (int kk = 0; kk < 4; kk++) {
            const float4 w = *(const float4*)(W + (k4 + kk) * DD + c);
#pragma unroll
            for (int i = 0; i < 4; i++) {
                const float xv = ((const float*)&xr[i])[kk];
                acc[i][0] = fmaf(xv, w.x, acc[i][0]);
                acc[i][1] = fmaf(xv, w.y, acc[i][1]);
                acc[i][2] = fmaf(xv, w.z, acc[i][2]);
                acc[i][3] = fmaf(xv, w.w, acc[i][3]);
            }
        }
    }
    const float4 bv  = *(const float4*)(b + c);
    const float4 awi = *(const float4*)(aW + c);
    const float4 awj = *(const float4*)(aW + DD + c);
    const float ep = 1.0f + eps_p[0];

    float pa[4], pb[4];
#pragma unroll
    for (int i = 0; i < 4; i++) {
        const long row = rowbase + r0 + i;
        float4 ov = { acc[i][0] + bv.x, acc[i][1] + bv.y,
                      acc[i][2] + bv.z, acc[i][3] + bv.w };
        uint2 pv = { pack_bf2(ov.x, ov.y), pack_bf2(ov.z, ov.w) };
        *(uint2*)(hb + row * 64 + (c >> 1)) = pv;
        uint2 zv = { pack_bf2(ep * ov.x, ep * ov.y),
                     pack_bf2(ep * ov.z, ep * ov.w) };
        *(uint2*)(zb + row * 64 + (c >> 1)) = zv;
        pa[i] = ov.x * awi.x + ov.y * awi.y + ov.z * awi.z + ov.w * awi.w;
        pb[i] = ov.x * awj.x + ov.y * awj.y + ov.z * awj.z + ov.w * awj.w;
    }
#pragma unroll
    for (int off = 1; off < 32; off <<= 1) {
#pragma unroll
        for (int i = 0; i < 4; i++) {
            pa[i] += __shfl_xor(pa[i], off, 64);
            pb[i] += __shfl_xor(pb[i], off, 64);
        }
    }
    if ((t & 31) == 0) {
#pragma unroll
        for (int i = 0; i < 4; i++) {
            pi[rowbase + r0 + i] = pa[i];
            pj[rowbase + r0 + i] = pb[i];
        }
    }
}

// ---------------------------------------------------------------------------
// weight transpose + bf16 cast (W1, W2, and edge_W -> col-major bf16)
__global__ __launch_bounds__(256) void wcast_kernel(
    const float* __restrict__ W1, const float* __restrict__ W2,
    const float* __restrict__ eW,
    unsigned short* __restrict__ w1t, unsigned short* __restrict__ w2t,
    unsigned short* __restrict__ ewt)
{
    const int idx = blockIdx.x * 256 + threadIdx.x;   // grid covers LL*32768
    const int l = idx >> 15, r = idx & 32767;
    {   const int n = r >> 7, k = r & 127;
        w1t[idx] = bf16r(W1[(l << 15) + (k << 8) + n]);
    }
    {   const int n = r >> 8, k = r & 255;
        w2t[idx] = bf16r(W2[(l << 15) + (k << 7) + n]);
    }
    if (idx < LL * 2048) {                            // ewt[l][n][k], n<128,k<16
        const int le = idx >> 11, re = idx & 2047;
        const int n = re >> 4, k = re & 15;
        ewt[idx] = bf16r(eW[(le << 11) + (k << 7) + n]);
    }
}

// ---------------------------------------------------------------------------
// CSR build
__global__ __launch_bounds__(256) void hist_kernel(
    const int* __restrict__ edge_index, int* __restrict__ counts)
{
    const int i = blockIdx.x * 256 + threadIdx.x;
    atomicAdd(&counts[edge_index[EE + i]], 1);
}

__global__ __launch_bounds__(256) void scan1_kernel(
    const int* __restrict__ counts, int* __restrict__ scanned,
    int* __restrict__ partials)
{
    __shared__ int sdata[256];
    const int t = threadIdx.x;
    const int base = blockIdx.x * 1024 + t * 4;
    int v[4]; int sum = 0;
#pragma unroll
    for (int i = 0; i < 4; i++) {
        const int idx = base + i;
        v[i] = (idx < NN) ? counts[idx] : 0;
        sum += v[i];
    }
    sdata[t] = sum;
    __syncthreads();
    for (int off = 1; off < 256; off <<= 1) {
        int x = (t >= off) ? sdata[t - off] : 0;
        __syncthreads();
        sdata[t] += x;
        __syncthreads();
    }
    int run = sdata[t] - sum;
#pragma unroll
    for (int i = 0; i < 4; i++) {
        const int idx = base + i;
        if (idx < NN) scanned[idx] = run;
        run += v[i];
    }
    if (t == 255) partials[blockIdx.x] = sdata[255];
}

__global__ void scan2_kernel(int* __restrict__ partials)
{
    if (threadIdx.x == 0) {
        int run = 0;
        for (int i = 0; i < 40; i++) { int v = partials[i]; partials[i] = run; run += v; }
    }
}

__global__ __launch_bounds__(256) void scan3_kernel(
    const int* __restrict__ scanned, const int* __restrict__ partials,
    int* __restrict__ offsets, int* __restrict__ cursor)
{
    const int idx = blockIdx.x * 256 + threadIdx.x;
    if (idx < NN) {
        const int off = scanned[idx] + partials[idx >> 10];
        offsets[idx] = off;
        cursor[idx]  = off;
    }
}

// scatter: pre-scaled src/dst streams + bf16-packed edge_attr at CSR position
__global__ __launch_bounds__(256) void scatter_kernel(
    const int* __restrict__ edge_index, const float* __restrict__ edge_attr,
    int* __restrict__ cursor,
    int* __restrict__ srcs_p, int* __restrict__ dstd_p,
    unsigned* __restrict__ ea_b)
{
    const int i = blockIdx.x * 256 + threadIdx.x;
    const int src = edge_index[i];
    const int dst = edge_index[EE + i];
    const int pos = atomicAdd(&cursor[dst], 1);
    srcs_p[pos] = src << 6;
    dstd_p[pos] = dst << 7;

    const float4* sp = (const float4*)(edge_attr + (long)i * EDD);
    const float4 s0 = sp[0], s1 = sp[1], s2 = sp[2], s3 = sp[3];
    uint4 o0 = { pack_bf2(s0.x, s0.y), pack_bf2(s0.z, s0.w),
                 pack_bf2(s1.x, s1.y), pack_bf2(s1.z, s1.w) };
    uint4 o1 = { pack_bf2(s2.x, s2.y), pack_bf2(s2.z, s2.w),
                 pack_bf2(s3.x, s3.y), pack_bf2(s3.z, s3.w) };
    *(uint4*)(ea_b + (long)pos * 8)     = o0;
    *(uint4*)(ea_b + (long)pos * 8 + 4) = o1;
}

// ---------------------------------------------------------------------------
// Edge aggregation v10 = v7 exactly (best measured: 68.5us), except the z
// segment flush is a single u32 bf16-pair RMW (z is bf16-packed end-to-end:
// its only consumer, mlp, stages it to bf16 anyway). Halves z traffic.
__global__ __launch_bounds__(256, 2) void edge_msg_kernel(
    const unsigned* __restrict__ hb, const unsigned* __restrict__ ea_b,
    const float* __restrict__ pi, const float* __restrict__ pj,
    const int* __restrict__ srcs_p, const int* __restrict__ dstd_p,
    const int* __restrict__ offsets, const float* __restrict__ ab_p,
    const unsigned short* __restrict__ eWt, const float* __restrict__ eb,
    unsigned* __restrict__ zb)
{
    __shared__ __align__(16) unsigned short et[4][32 * DD];   // 8 KB per wave

    const int t = threadIdx.x;
    const int wid = t >> 6, lane = t & 63;
    const int n0 = (blockIdx.x * 4 + wid) * KPW;   // first owned dst node
    const int ebeg = offsets[n0];
    const int eend = (n0 + KPW < NN) ? offsets[n0 + KPW] : EE;

    const int l31 = lane & 31, half = lane >> 5;
    bf16x8 bfr[4];
#pragma unroll
    for (int nt = 0; nt < 4; nt++)
        bfr[nt] = *(const bf16x8*)(eWt + (nt * 32 + l31) * 16 + half * 8);
    float ebv[4];
#pragma unroll
    for (int nt = 0; nt < 4; nt++) ebv[nt] = eb[nt * 32 + l31];
    const float ab0 = ab_p[0];
    const int rb = 4 * half;                 // MFMA C row base (32x32 layout)
    unsigned short* etw = et[wid];
    const int c0 = lane * 2;
    const f32x2 zero2 = { 0.0f, 0.0f };
    const f32x16 vz16 = {0.0f,0.0f,0.0f,0.0f, 0.0f,0.0f,0.0f,0.0f,
                         0.0f,0.0f,0.0f,0.0f, 0.0f,0.0f,0.0f,0.0f};

    f32x2 acc = zero2;
    int cur = -1;                            // current dst (as dst*128), uniform

    // flush accumulated pair into bf16-packed z (exclusive ownership, no race)
    auto flushz = [&](int curv) {
        const int zo = (curv >> 1) + lane;   // dst*64 + lane
        const unsigned uz = zb[zo];
        const float lo = __uint_as_float(uz << 16)         + acc[0];
        const float hi = __uint_as_float(uz & 0xffff0000u) + acc[1];
        zb[zo] = pack_bf2(lo, hi);
    };

    for (int e = ebeg; e < eend; e += 32) {
        const int rem = eend - e;
        const int nv = rem < 32 ? rem : 32;

        // ---- meta for 32 edges on lanes (duplicated across halves) ----
        const int ce = min(e + l31, EE - 1);
        const int ss = srcs_p[ce];           // src*64
        const int dd = dstd_p[ce];           // dst*128
        const float s  = pi[dd >> 7] + pj[ss >> 6] + ab0;
        const float av = 1.0f / (1.0f + expf(-s));
        const unsigned avu = __float_as_uint(av);

        // helper: consume one edge (index j in tile, gathered word uj).
        // j is a compile-time constant at every call site -> v_readlane.
        auto consume = [&](int j, unsigned uj) {
            const int ddj = __builtin_amdgcn_readlane(dd, j);
            if (ddj != cur) {                // wave-uniform (scalar compare)
                if (cur >= 0) flushz(cur);
                acc = zero2; cur = ddj;
            }
            const float aj = __uint_as_float(__builtin_amdgcn_readlane(avu, j));
            const unsigned el = (unsigned)etw[j * DD + c0];
            const unsigned eh = (unsigned)etw[j * DD + c0 + 1];
            const f32x2 ev = { __uint_as_float(el << 16),
                               __uint_as_float(eh << 16) };
            const f32x2 xj = { __uint_as_float(uj << 16),
                               __uint_as_float(uj & 0xffff0000u) };
            const f32x2 avv = { aj, aj };
            f32x2 m = __builtin_elementwise_fma(xj, avv, ev);
            m = __builtin_elementwise_max(m, zero2);
            acc += m;
        };

        // ---- gather half 0 early; drains under the MFMA phase ----
        unsigned u0[16];
#pragma unroll
        for (int j = 0; j < 16; j++)
            if (j < nv) u0[j] = hb[__shfl(ss, j, 64) + lane];

        // ---- e = ea @ eW + eb on the matrix pipe -> wave-private bf16 LDS ----
        const bf16x8 afr = *(const bf16x8*)(ea_b + (long)ce * 8 + half * 4);
#pragma unroll
        for (int p = 0; p < 2; p++) {
            f32x16 a0 = vz16, a1 = vz16;
            a0 = __builtin_amdgcn_mfma_f32_32x32x16_bf16(afr, bfr[2 * p],     a0, 0, 0, 0);
            a1 = __builtin_amdgcn_mfma_f32_32x32x16_bf16(afr, bfr[2 * p + 1], a1, 0, 0, 0);
#pragma unroll
            for (int r = 0; r < 16; r++) {
                const int row = rb + (r & 3) + 8 * (r >> 2);
                etw[row * DD + (2 * p)     * 32 + l31] = bf16r(a0[r] + ebv[2 * p]);
                etw[row * DD + (2 * p + 1) * 32 + l31] = bf16r(a1[r] + ebv[2 * p + 1]);
            }
        }
        asm volatile("" ::: "memory");       // phase fence: stores before loads

        // ---- gather half 1; drains under consume of half 0 ----
        unsigned u1[16];
#pragma unroll
        for (int j = 0; j < 16; j++)
            if (16 + j < nv) u1[j] = hb[__shfl(ss, 16 + j, 64) + lane];

        // ---- consume half 0, then half 1 (constant indexing, no spills) ----
#pragma unroll
        for (int j = 0; j < 16; j++) {
            if (j >= nv) break;              // wave-uniform
            consume(j, u0[j]);
        }
#pragma unroll
        for (int j = 0; j < 16; j++) {
            if (16 + j >= nv) break;         // wave-uniform
            consume(16 + j, u1[j]);
        }
        asm volatile("" ::: "memory");       // phase fence: loads before next stores
    }
    if (cur >= 0) flushz(cur);
}

// ---------------------------------------------------------------------------
// Fused GIN MLP via bf16 MFMA, N-SPLIT (unchanged math). Traffic dead-store
// fixes: zin is bf16-packed (stage = pure uint4 copy, -10.5MB read); the
// fp32 `out` is written ONLY at the last layer (l<2's out/h was dead,
// -20.5MB); hb/z/pi/pj written only when a next layer consumes them (l<2).
__global__ __launch_bounds__(256) void mlp_mfma_kernel(
    const unsigned* __restrict__ zin,
    const unsigned short* __restrict__ w1t, const unsigned short* __restrict__ w2t,
    const float* __restrict__ b1, const float* __restrict__ g1, const float* __restrict__ bb1,
    const float* __restrict__ b2, const float* __restrict__ g2, const float* __restrict__ bb2,
    const float* __restrict__ aWn, const float* __restrict__ epsn_p,
    float* __restrict__ out, unsigned* __restrict__ hb,
    float* __restrict__ pi, float* __restrict__ pj, unsigned* __restrict__ zb,
    const int do_relu)
{
    __shared__ __align__(16) unsigned short zsb[64][136];   // 128 + 8 pad
    __shared__ __align__(16) unsigned short usb[64][264];   // 256 + 8 pad
    __shared__ float sh_pi[64], sh_pj[64];
    const int t = threadIdx.x;
    const int wid = t >> 6, lane = t & 63;
    const long rowbase = (long)blockIdx.x * 64;

    if (t < 64) { sh_pi[t] = 0.0f; sh_pj[t] = 0.0f; }

    // stage z (bf16-packed) -> zsb: pure uint4 copy, no conversion
    {
        const uint4* z4 = (const uint4*)(zin + rowbase * 64);
#pragma unroll
        for (int i = 0; i < 4; i++) {
            const int idx = t + i * 256;          // 1024 uint4 = 64 rows x 16
            const int row = idx >> 4;
            const int q   = idx & 15;             // 8 bf16 per uint4
            *(uint4*)&zsb[row][q * 8] = z4[idx];
        }
    }
    __syncthreads();

    const int mrow  = lane & 15;
    const int quad  = lane >> 4;
    const f32x4 vzero = {0.0f, 0.0f, 0.0f, 0.0f};

    // ---- phase 1: wave owns nt = wid*4 .. wid*4+3 (cols) for all 64 rows ----
    {
        const int nt0 = wid * 4;
        bf16x8 bf[4][4];                      // [j][ks]
#pragma unroll
        for (int j = 0; j < 4; j++) {
            const unsigned short* wp = w1t + ((nt0 + j) * 16 + mrow) * 128 + quad * 8;
#pragma unroll
            for (int ks = 0; ks < 4; ks++)
                bf[j][ks] = *(const bf16x8*)(wp + ks * 32);
        }
        float gg[4], bi[4], bt[4];
#pragma unroll
        for (int j = 0; j < 4; j++) {
            const int c = (nt0 + j) * 16 + mrow;
            gg[j] = g1[c]; bi[j] = b1[c]; bt[j] = bb1[c];
        }
#pragma unroll
        for (int rt = 0; rt < 4; rt++) {
            bf16x8 af[4];
#pragma unroll
            for (int ks = 0; ks < 4; ks++)
                af[ks] = *(const bf16x8*)&zsb[rt * 16 + mrow][ks * 32 + quad * 8];
            f32x4 acc[4];
#pragma unroll
            for (int j = 0; j < 4; j++) acc[j] = vzero;
#pragma unroll
            for (int j = 0; j < 4; j++)
#pragma unroll
                for (int ks = 0; ks < 4; ks++)
                    acc[j] = __builtin_amdgcn_mfma_f32_16x16x32_bf16(af[ks], bf[j][ks], acc[j], 0, 0, 0);
            // epilogue 1 for this row tile
#pragma unroll
            for (int j = 0; j < 4; j++) {
                const int c = (nt0 + j) * 16 + mrow;
#pragma unroll
                for (int r = 0; r < 4; r++) {
                    const int row = rt * 16 + quad * 4 + r;
                    const float u = fmaxf(fmaf(gg[j] * (acc[j][r] + bi[j]), kBnInv, bt[j]), 0.0f);
                    const float up = __shfl_xor(u, 1, 64);
                    if ((mrow & 1) == 0)
                        *(unsigned*)&usb[row][c] = pack_bf2(u, up);
                }
            }
        }
    }
    __syncthreads();

    // ---- phase 2: wave owns nt = wid*2, wid*2+1 for all 64 rows ----
    {
        const int nt0 = wid * 2;
        bf16x8 bf[2][8];
#pragma unroll
        for (int j = 0; j < 2; j++) {
            const unsigned short* wp = w2t + ((nt0 + j) * 16 + mrow) * 256 + quad * 8;
#pragma unroll
            for (int ks = 0; ks < 8; ks++)
                bf[j][ks] = *(const bf16x8*)(wp + ks * 32);
        }
        float gg[2], bi[2], bt[2], awi[2], awj[2];
#pragma unroll
        for (int j = 0; j < 2; j++) {
            const int c = (nt0 + j) * 16 + mrow;
            gg[j] = g2[c]; bi[j] = b2[c]; bt[j] = bb2[c];
            awi[j] = aWn[c]; awj[j] = aWn[DD + c];
        }
        const float epn = do_relu ? (1.0f + epsn_p[0]) : 0.0f;

#pragma unroll
        for (int rt = 0; rt < 4; rt++) {
            bf16x8 af[8];
#pragma unroll
            for (int ks = 0; ks < 8; ks++)
                af[ks] = *(const bf16x8*)&usb[rt * 16 + mrow][ks * 32 + quad * 8];
            f32x4 acc[2];
            acc[0] = vzero; acc[1] = vzero;
#pragma unroll
            for (int j = 0; j < 2; j++)
#pragma unroll
                for (int ks = 0; ks < 8; ks++)
                    acc[j] = __builtin_amdgcn_mfma_f32_16x16x32_bf16(af[ks], bf[j][ks], acc[j], 0, 0, 0);

            float si[4] = {0, 0, 0, 0}, sj[4] = {0, 0, 0, 0};
#pragma unroll
            for (int j = 0; j < 2; j++) {
                const int c = (nt0 + j) * 16 + mrow;
#pragma unroll
                for (int r = 0; r < 4; r++) {
                    const long row = rowbase + rt * 16 + quad * 4 + r;
                    float v = fmaf(gg[j] * (acc[j][r] + bi[j]), kBnInv, bt[j]);
                    if (do_relu) {
                        // intermediate layer: produce hb + bf16 z + attn partials
                        v = fmaxf(v, 0.0f);
                        si[r] = fmaf(v, awi[j], si[r]);
                        sj[r] = fmaf(v, awj[j], sj[r]);
                        const float vp = __shfl_xor(v, 1, 64);
                        if ((mrow & 1) == 0) {
                            hb[row * 64 + (c >> 1)] = pack_bf2(v, vp);
                            zb[row * 64 + (c >> 1)] = pack_bf2(epn * v, epn * vp);
                        }
                    } else {
                        // final layer: fp32 output only
                        out[row * DD + c] = v;
                    }
                }
            }
            if (do_relu) {
#pragma unroll
                for (int off = 1; off < 16; off <<= 1) {
#pragma unroll
                    for (int r = 0; r < 4; r++) {
                        si[r] += __shfl_xor(si[r], off, 64);
                        sj[r] += __shfl_xor(sj[r], off, 64);
                    }
                }
                if (mrow == 0) {
#pragma unroll
                    for (int r = 0; r < 4; r++) {
                        atomicAdd(&sh_pi[rt * 16 + quad * 4 + r], si[r]);
                        atomicAdd(&sh_pj[rt * 16 + quad * 4 + r], sj[r]);
                    }
                }
            }
        }
    }
    if (do_relu) {
        __syncthreads();
        if (t < 64) {
            pi[rowbase + t] = sh_pi[t];
            pj[rowbase + t] = sh_pj[t];
        }
    }
}

// ---------------------------------------------------------------------------
extern "C" void kernel_launch(void* const* d_in, const int* in_sizes, int n_in,
                              void* d_out, int out_size, void* d_ws, size_t ws_size,
                              hipStream_t stream)
{
    const float* x         = (const float*)d_in[0];
    const float* edge_attr = (const float*)d_in[1];
    const float* node_W    = (const float*)d_in[2];
    const float* node_b    = (const float*)d_in[3];
    const float* edge_W    = (const float*)d_in[4];
    const float* edge_b    = (const float*)d_in[5];
    const float* attn_W    = (const float*)d_in[6];
    const float* attn_b    = (const float*)d_in[7];
    const float* eps       = (const float*)d_in[8];
    const float* W1        = (const float*)d_in[9];
    const float* b1        = (const float*)d_in[10];
    const float* bn1_g     = (const float*)d_in[11];
    const float* bn1_b     = (const float*)d_in[12];
    const float* W2        = (const float*)d_in[13];
    const float* b2        = (const float*)d_in[14];
    const float* bn_g      = (const float*)d_in[15];
    const float* bn_b      = (const float*)d_in[16];
    const int*   edge_index= (const int*)d_in[17];

    unsigned* zb   = (unsigned*)d_ws;                    // [N*64] bf16-packed z
    float* pi      = (float*)(zb + (size_t)NN * 64);     // [N]
    float* pj      = pi + NN;                            // [N]
    unsigned* ea_b = (unsigned*)(pj + NN);               // [E*8] packed bf16
    unsigned* hbuf = ea_b + (size_t)EE * 8;              // [N*64]
    unsigned short* w1t = (unsigned short*)(hbuf + (size_t)NN * 64); // [L*32768]
    unsigned short* w2t = w1t + (size_t)LL * 32768;                  // [L*32768]
    unsigned short* ewt = w2t + (size_t)LL * 32768;      // [L*2048] eW col-major bf16
    int* counts  = (int*)(ewt + (size_t)LL * 2048);      // [N]
    int* offsets = counts + NN;                          // [N]
    int* cursor  = offsets + NN;                         // [N]
    int* scanned = cursor + NN;                          // [40960]
    int* partials= scanned + 40960;                      // [64]
    int* srcs_p  = partials + 64;                        // [E] (src*64)
    int* dstd_p  = srcs_p + EE;                          // [E] (dst*128)
    float* out = (float*)d_out;

    node_enc_kernel<<<NN / 32, 256, 0, stream>>>(
        x, node_W, node_b, attn_W, eps, hbuf, pi, pj, zb);
    wcast_kernel<<<LL * 128, 256, 0, stream>>>(W1, W2, edge_W, w1t, w2t, ewt);

    hipMemsetAsync(counts, 0, NN * sizeof(int), stream);
    hist_kernel<<<EE / 256, 256, 0, stream>>>(edge_index, counts);
    scan1_kernel<<<40, 256, 0, stream>>>(counts, scanned, partials);
    scan2_kernel<<<1, 64, 0, stream>>>(partials);
    scan3_kernel<<<(NN + 255) / 256, 256, 0, stream>>>(scanned, partials, offsets, cursor);
    scatter_kernel<<<EE / 256, 256, 0, stream>>>(
        edge_index, edge_attr, cursor, srcs_p, dstd_p, ea_b);

    for (int l = 0; l < LL; l++) {
        const int ln = (l + 1 < LL) ? (l + 1) : l;   // next-layer attn/eps (dummy at last)
        edge_msg_kernel<<<NN / (4 * KPW), 256, 0, stream>>>(
            hbuf, ea_b, pi, pj, srcs_p, dstd_p, offsets, attn_b + l,
            ewt + (size_t)l * 2048, edge_b + (size_t)l * DD, zb);
        mlp_mfma_kernel<<<NN / 64, 256, 0, stream>>>(
            zb,
            w1t + (size_t)l * 32768, w2t + (size_t)l * 32768,
            b1 + (size_t)l * 2 * DD, bn1_g + (size_t)l * 2 * DD, bn1_b + (size_t)l * 2 * DD,
            b2 + (size_t)l * DD, bn_g + (size_t)l * DD, bn_b + (size_t)l * DD,
            attn_W + (size_t)ln * 2 * DD, eps + ln,
            out, hbuf, pi, pj, zb, (l < LL - 1) ? 1 : 0);
    }
}